// Round 5
// baseline (139.779 us; speedup 1.0000x reference)
//
#include <hip/hip_runtime.h>

typedef __attribute__((ext_vector_type(4))) float f32x4;
typedef __attribute__((ext_vector_type(8))) short short8;
typedef unsigned short ushort_t;

constexpr int DM = 1024, DH = 64, S = 4096, B = 4;
// fold softmax scale 1/sqrt(64) AND log2(e) into Q so scores are in exp2 units
constexpr float QSCALE = 0.125f * 1.44269504088896340736f;
constexpr int SPLIT = 4;

// ws layout (bytes)
constexpr size_t WBT_OFF = 0;                    // Wbt: [192][1024] bf16 (W transposed)
constexpr size_t QB_OFF  = 393216;               // Qb:  [B*S][64] bf16, pre-scaled
constexpr size_t KB_OFF  = QB_OFF + 2097152;     // Kb:  [B*S][64] bf16, chunk-swizzled
constexpr size_t VT_OFF  = KB_OFF + 2097152;     // Vtb: [B][64][S] bf16, chunk-swizzled
constexpr size_t ML_OFF  = VT_OFF + 2097152;     // ml:  f32 [SPLIT][B*S][2] = 512KB
constexpr size_t PO_OFF  = ML_OFF + 524288;      // po:  bf16 [SPLIT][B*S][64] = 8MB

__device__ __forceinline__ ushort_t f2bf(float f) {  // RNE f32->bf16
    unsigned u = __float_as_uint(f);
    u += 0x7FFFu + ((u >> 16) & 1u);
    return (ushort_t)(u >> 16);
}

__device__ __forceinline__ void gl_lds16(const void* g, void* l) {
    __builtin_amdgcn_global_load_lds(
        (const __attribute__((address_space(1))) unsigned int*)g,
        (__attribute__((address_space(3))) unsigned int*)l, 16, 0, 0);
}

// ---------------- prep: W fp32 [1024][64] -> Wbt bf16 [192][1024] (transposed) ----
__global__ __launch_bounds__(256) void prep_w_kernel(
    const float* __restrict__ Wq, const float* __restrict__ Wk,
    const float* __restrict__ Wv, ushort_t* __restrict__ wbt)
{
    const int n = blockIdx.x;            // 0..191 : [Q(0-63)|K(64-127)|V(128-191)]
    const int p = n >> 6, d = n & 63;
    const float* W = (p == 0) ? Wq : (p == 1) ? Wk : Wv;
    const int k0 = threadIdx.x * 4;
    ushort4 pack;
    pack.x = f2bf(W[(k0 + 0) * DH + d]);
    pack.y = f2bf(W[(k0 + 1) * DH + d]);
    pack.z = f2bf(W[(k0 + 2) * DH + d]);
    pack.w = f2bf(W[(k0 + 3) * DH + d]);
    *reinterpret_cast<ushort4*>(wbt + (size_t)n * DM + k0) = pack;
}

// ---------------- QKV projection: cooperative staged GEMM ----------------
// Block = 512 thr (8 waves) on 32 rows. Wave = (sub = m-subtile of 16 rows,
// np = n-quarter of 3 nt). Per 32-k step: stage A [32r][32k] f32 (4KB) +
// B [192n][32k] bf16 (12KB) into dbuf LDS via global_load_lds (pre-swizzled
// src, linear dst); each wave: 2 A ds_reads + cvt, 3 x (B ds_read + MFMA).
// n-split -> no cross-wave reduction. 512 blocks x 8 waves = 4096 waves (4/SIMD).
__global__ __launch_bounds__(512, 4) void qkv_mfma_kernel(
    const float* __restrict__ x, const ushort_t* __restrict__ wbt,
    const float* __restrict__ bq, const float* __restrict__ bk,
    const float* __restrict__ bv,
    ushort_t* __restrict__ qb, ushort_t* __restrict__ kb, ushort_t* __restrict__ vt)
{
    __shared__ uint4 AsU[2][256];   // 2 x 4KB : [32 r][128B], 16B-chunk swz ch^(row&7)
    __shared__ uint4 BsU[2][768];   // 2 x 12KB: [192 n][64B], 16B-chunk swz ch^(row&3)

    const int tid = threadIdx.x;
    const int wid = tid >> 6, lane = tid & 63;
    const int q16 = lane & 15, lg = lane >> 4;
    const int sub = wid & 1, np = wid >> 1;
    const int r0 = blockIdx.x * 32;
    const char* xB = (const char*)x;
    const char* wB = (const char*)wbt;

    auto task = [&](int tk, int buf, int kk) {
        if (tk < 4) {
            // A seg tk (1KB = 8 rows x 128B); row&7 == lane>>3 (seg*8 aligned)
            gl_lds16(xB + (size_t)(r0 + tk * 8 + (lane >> 3)) * 4096 + kk * 4
                        + (((lane & 7) ^ (lane >> 3)) << 4),
                     (char*)&AsU[buf][0] + tk * 1024 + lane * 16);
        } else {
            const int sg = tk - 4;   // B seg 0..11 (1KB = 16 n-rows x 64B)
            gl_lds16(wB + (size_t)(sg * 16 + (lane >> 2)) * 2048 + kk * 2
                        + ((((lane & 3) ^ ((lane >> 2) & 3))) << 4),
                     (char*)&BsU[buf][0] + sg * 1024 + lane * 16);
        }
    };

    f32x4 acc[3];
#pragma unroll
    for (int j = 0; j < 3; ++j) acc[j] = {0.f, 0.f, 0.f, 0.f};

    // prologue: stage step 0 into buf 0 (16 tasks over 8 waves)
    task(2 * wid, 0, 0);
    task(2 * wid + 1, 0, 0);
    __syncthreads();

    const int row = sub * 16 + q16;
    for (int s = 0; s < 32; ++s) {
        const int buf = s & 1;
        if (s + 1 < 32) {   // prefetch next step into other buffer
            task(2 * wid, buf ^ 1, (s + 1) * 32);
            task(2 * wid + 1, buf ^ 1, (s + 1) * 32);
        }
        const char* AsC = (const char*)&AsU[buf][0];
        const char* BsC = (const char*)&BsU[buf][0];
        const f32x4 a0 = *(const f32x4*)(AsC + row * 128 + (((2 * lg) ^ (row & 7)) << 4));
        const f32x4 a1 = *(const f32x4*)(AsC + row * 128 + (((2 * lg + 1) ^ (row & 7)) << 4));
        short8 Af;
        Af[0] = (short)f2bf(a0[0]); Af[1] = (short)f2bf(a0[1]);
        Af[2] = (short)f2bf(a0[2]); Af[3] = (short)f2bf(a0[3]);
        Af[4] = (short)f2bf(a1[0]); Af[5] = (short)f2bf(a1[1]);
        Af[6] = (short)f2bf(a1[2]); Af[7] = (short)f2bf(a1[3]);
        __builtin_amdgcn_s_setprio(1);
#pragma unroll
        for (int j = 0; j < 3; ++j) {
            const int nt = np * 3 + j;
            const short8 Bf = *(const short8*)(
                BsC + (nt * 16 + q16) * 64 + ((lg ^ (q16 & 3)) << 4));
            acc[j] = __builtin_amdgcn_mfma_f32_16x16x32_bf16(Af, Bf, acc[j], 0, 0, 0);
        }
        __builtin_amdgcn_s_setprio(0);
        __syncthreads();   // drains prefetch vmcnt + guards buf reuse
    }

    // Epilogue: C/D layout row=(lane>>4)*4+reg, col=lane&15.
#pragma unroll
    for (int j = 0; j < 3; ++j) {
        const int nt = np * 3 + j;
        const int p = nt >> 2, d = ((nt & 3) << 4) + q16;
        const float* bp = (p == 0) ? bq : (p == 1) ? bk : bv;
        const float bb = bp[d];
#pragma unroll
        for (int r = 0; r < 4; ++r) {
            const int m = r0 + sub * 16 + (lg << 2) + r;
            const float v = acc[j][r] + bb;
            if (p == 0) {
                qb[(size_t)m * 64 + d] = f2bf(v * QSCALE);
            } else if (p == 1) {
                kb[(size_t)m * 64 + (((d >> 3) ^ (m & 7)) << 3) + (d & 7)] = f2bf(v);
            } else {
                const int bb_ = m >> 12, sx = m & 4095;
                vt[(size_t)bb_ * 262144 + (size_t)d * 4096 + (sx & ~63)
                   + ((((sx >> 3) & 7) ^ (d & 7)) << 3) + (sx & 7)] = f2bf(v);
            }
        }
    }
}

// ---------------- causal flash attention: grid split-KV x4 ----------------
// Block = 128 thr (2 waves), 32 q-rows (sub picks 16). z = blockIdx.y in [0,4):
// tiles t = z, z+4, ... < ntiles. LDS exactly 20480B -> 8 blocks/CU (4 w/SIMD).
// Staging: T14 reg-staged (global->reg issued before compute; ds_write between
// barriers). Partial (o bf16, m/l f32) to ws; merge kernel normalizes.
__global__ __launch_bounds__(128, 4) void attn_mfma_kernel(
    const ushort_t* __restrict__ qb, const ushort_t* __restrict__ kb,
    const ushort_t* __restrict__ vt, ushort_t* __restrict__ po,
    float* __restrict__ ml)
{
    __shared__ uint4 LsU[1024];        // 16KB: K 8KB + V 8KB (chunk-swizzled)
    __shared__ uint2 PsU[2][256];      // 4KB: per-wave P [16 q][64 kv] bf16

    const int tid = threadIdx.x;
    const int sub = tid >> 6, lane = tid & 63;
    const int q16 = lane & 15, lg = lane >> 4;
    const int z = blockIdx.y;

    // XCD-chunked mapping; idx ascending -> qt descending (heavy diagonal first).
    const int linear = blockIdx.x;            // 0..511
    const int xcd = linear & 7, idx = linear >> 3;
    const int b = xcd >> 1;
    const int qt = 127 - (idx * 2 + (xcd & 1));

    const int qrow = qt * 32 + sub * 16 + q16;            // this lane's q (column)
    const char* QbB = (const char*)qb + (size_t)b * S * 128;
    const char* KbB = (const char*)kb + (size_t)b * S * 128;
    const char* VtB = (const char*)vt + (size_t)b * 64 * S * 2;

    const short8 qf0 = *reinterpret_cast<const short8*>(QbB + ((size_t)qrow * 64 + lg * 8) * 2);
    const short8 qf1 = *reinterpret_cast<const short8*>(QbB + ((size_t)qrow * 64 + 32 + lg * 8) * 2);

    f32x4 o[4];
#pragma unroll
    for (int nt = 0; nt < 4; ++nt) o[nt] = {0.f, 0.f, 0.f, 0.f};
    float m = -1e30f, l = 0.f;

    char* KsC = (char*)LsU;
    char* VsC = KsC + 8192;
    char* PsC = (char*)&PsU[sub][0];

    const int ntiles = (qt * 32 + 31) / 64 + 1;

    uint4 kreg[4], vreg[4];
    auto loadregs = [&](int t) {
        const int kv0 = t * 64;
#pragma unroll
        for (int sg = 0; sg < 4; ++sg) {
            const int seg = sub * 4 + sg;   // wave-uniform
            kreg[sg] = *(const uint4*)(KbB + (size_t)kv0 * 128 + seg * 1024 + lane * 16);
            const int vd = seg * 8 + (lane >> 3);
            vreg[sg] = *(const uint4*)(VtB + ((size_t)vd * S + kv0) * 2 + (lane & 7) * 16);
        }
    };
    auto writelds = [&]() {
#pragma unroll
        for (int sg = 0; sg < 4; ++sg) {
            const int seg = sub * 4 + sg;
            *(uint4*)(KsC + seg * 1024 + lane * 16) = kreg[sg];
            *(uint4*)(VsC + seg * 1024 + lane * 16) = vreg[sg];
        }
    };

    int t = z;
    if (t < ntiles) { loadregs(t); writelds(); }
    __syncthreads();

    for (; t < ntiles; t += SPLIT) {
        const int tn = t + SPLIT;
        if (tn < ntiles) loadregs(tn);   // HBM/L2 latency hides under compute
        const int kv0 = t * 64;

        // ---- S^T = K . Q^T : D[kv][q], lane has q=q16, kv = kv0+16mt+4lg+r ----
        f32x4 st[4];
#pragma unroll
        for (int mt = 0; mt < 4; ++mt) st[mt] = {0.f, 0.f, 0.f, 0.f};
        __builtin_amdgcn_s_setprio(1);
#pragma unroll
        for (int ks = 0; ks < 2; ++ks) {
#pragma unroll
            for (int mt = 0; mt < 4; ++mt) {
                const short8 kf = *reinterpret_cast<const short8*>(
                    KsC + (mt * 16 + q16) * 128 + (((lg + 4 * ks) ^ (q16 & 7)) << 4));
                st[mt] = __builtin_amdgcn_mfma_f32_16x16x32_bf16(
                    kf, (ks ? qf1 : qf0), st[mt], 0, 0, 0);
            }
        }
        __builtin_amdgcn_s_setprio(0);

        // ---- causal mask (boundary tiles only; wave-uniform branch) ----
        if (kv0 + 63 > qt * 32 + sub * 16) {
#pragma unroll
            for (int mt = 0; mt < 4; ++mt)
#pragma unroll
                for (int r = 0; r < 4; ++r)
                    if (kv0 + mt * 16 + (lg << 2) + r > qrow) st[mt][r] = -1e30f;
        }

        // ---- online softmax (log2 units), per q-column q16 ----
        float tm = -1e30f;
#pragma unroll
        for (int mt = 0; mt < 4; ++mt)
#pragma unroll
            for (int r = 0; r < 4; ++r) tm = fmaxf(tm, st[mt][r]);
        tm = fmaxf(tm, __shfl_xor(tm, 16));
        tm = fmaxf(tm, __shfl_xor(tm, 32));
        const float mn = fmaxf(m, tm);
        const float corr = exp2f(m - mn);
        float ps = 0.f;
#pragma unroll
        for (int mt = 0; mt < 4; ++mt)
#pragma unroll
            for (int r = 0; r < 4; ++r) {
                const float pv = exp2f(st[mt][r] - mn);
                st[mt][r] = pv;
                ps += pv;
            }
        ps += __shfl_xor(ps, 16);
        ps += __shfl_xor(ps, 32);
        l = l * corr + ps;
        m = mn;

        // o rows are q = 4lg+r but corr is per q-col q16 -> redistribute.
        float corr_row[4];
#pragma unroll
        for (int r = 0; r < 4; ++r) corr_row[r] = __shfl(corr, (lg << 2) | r);
#pragma unroll
        for (int nt = 0; nt < 4; ++nt)
#pragma unroll
            for (int r = 0; r < 4; ++r) o[nt][r] *= corr_row[r];

        // ---- P (bf16) -> per-wave LDS, swizzled; readback as PV A-frags ----
#pragma unroll
        for (int mt = 0; mt < 4; ++mt) {
            uint2 w;
            w.x = (unsigned)f2bf(st[mt][0]) | ((unsigned)f2bf(st[mt][1]) << 16);
            w.y = (unsigned)f2bf(st[mt][2]) | ((unsigned)f2bf(st[mt][3]) << 16);
            const int ch = (2 * mt + (lg >> 1)) ^ (q16 & 7);
            *reinterpret_cast<uint2*>(PsC + q16 * 128 + ch * 16 + (lg & 1) * 8) = w;
        }
        const short8 pa0 = *reinterpret_cast<const short8*>(
            PsC + q16 * 128 + ((lg ^ (q16 & 7)) << 4));
        const short8 pa1 = *reinterpret_cast<const short8*>(
            PsC + q16 * 128 + (((lg + 4) ^ (q16 & 7)) << 4));

        // ---- O += P . V : D[q][d], row=4lg+r, col=16nt+q16 ----
        __builtin_amdgcn_s_setprio(1);
#pragma unroll
        for (int ks = 0; ks < 2; ++ks) {
#pragma unroll
            for (int nt = 0; nt < 4; ++nt) {
                const short8 vf = *reinterpret_cast<const short8*>(
                    VsC + (nt * 16 + q16) * 128 + (((lg + 4 * ks) ^ (q16 & 7)) << 4));
                o[nt] = __builtin_amdgcn_mfma_f32_16x16x32_bf16(
                    (ks ? pa1 : pa0), vf, o[nt], 0, 0, 0);
            }
        }
        __builtin_amdgcn_s_setprio(0);

        __syncthreads();                     // readers done with Ls
        if (tn < ntiles) writelds();         // stage next tile (waits its vmcnt)
        __syncthreads();                     // Ls ready for next iteration
    }

    // ---- partial write: o unnormalized (bf16), (m,l) f32 ----
    const int rowbase = qt * 32 + sub * 16;
    const size_t zb = (size_t)z * B * S + (size_t)b * S;
#pragma unroll
    for (int nt = 0; nt < 4; ++nt)
#pragma unroll
        for (int r = 0; r < 4; ++r)
            po[(zb + rowbase + (lg << 2) + r) * 64 + nt * 16 + q16] = f2bf(o[nt][r]);
    if (lg == 0) {
        ml[(zb + rowbase + q16) * 2 + 0] = m;
        ml[(zb + rowbase + q16) * 2 + 1] = l;
    }
}

// ---------------- merge: out = sum_z c_z * o_z / sum_z c_z * l_z ----------------
__global__ __launch_bounds__(256) void merge_kernel(
    const ushort_t* __restrict__ po, const float* __restrict__ ml,
    float* __restrict__ out)
{
    const int idx = blockIdx.x * 256 + threadIdx.x;   // 0 .. B*S*8-1
    const int row = idx >> 3, c8 = idx & 7;

    float mv[SPLIT], lv[SPLIT];
#pragma unroll
    for (int zz = 0; zz < SPLIT; ++zz) {
        const float2 t = *(const float2*)(ml + ((size_t)zz * B * S + row) * 2);
        mv[zz] = t.x; lv[zz] = t.y;
    }
    const float mm = fmaxf(fmaxf(mv[0], mv[1]), fmaxf(mv[2], mv[3]));
    float L = 0.f, cz[SPLIT];
#pragma unroll
    for (int zz = 0; zz < SPLIT; ++zz) { cz[zz] = exp2f(mv[zz] - mm); L += lv[zz] * cz[zz]; }
    const float inv = 1.0f / L;

    float acc[8];
#pragma unroll
    for (int e = 0; e < 8; ++e) acc[e] = 0.f;
#pragma unroll
    for (int zz = 0; zz < SPLIT; ++zz) {
        const uint4 pk = *(const uint4*)(po + ((size_t)zz * B * S + row) * 64 + c8 * 8);
        const unsigned w[4] = {pk.x, pk.y, pk.z, pk.w};
#pragma unroll
        for (int i = 0; i < 4; ++i) {
            acc[2 * i + 0] += cz[zz] * __uint_as_float((w[i] & 0xFFFFu) << 16);
            acc[2 * i + 1] += cz[zz] * __uint_as_float((w[i] >> 16) << 16);
        }
    }
    float4 o0 = make_float4(acc[0] * inv, acc[1] * inv, acc[2] * inv, acc[3] * inv);
    float4 o1 = make_float4(acc[4] * inv, acc[5] * inv, acc[6] * inv, acc[7] * inv);
    *(float4*)(out + (size_t)row * 64 + c8 * 8 + 0) = o0;
    *(float4*)(out + (size_t)row * 64 + c8 * 8 + 4) = o1;
}

extern "C" void kernel_launch(void* const* d_in, const int* in_sizes, int n_in,
                              void* d_out, int out_size, void* d_ws, size_t ws_size,
                              hipStream_t stream) {
    const float* x  = (const float*)d_in[0];
    const float* Wq = (const float*)d_in[1];
    const float* bq = (const float*)d_in[2];
    const float* Wk = (const float*)d_in[3];
    const float* bk = (const float*)d_in[4];
    const float* Wv = (const float*)d_in[5];
    const float* bv = (const float*)d_in[6];
    float* out = (float*)d_out;

    char* ws = (char*)d_ws;
    ushort_t* wbt = (ushort_t*)(ws + WBT_OFF);
    ushort_t* qbp = (ushort_t*)(ws + QB_OFF);
    ushort_t* kbp = (ushort_t*)(ws + KB_OFF);
    ushort_t* vtp = (ushort_t*)(ws + VT_OFF);
    float*    mlp = (float*)(ws + ML_OFF);
    ushort_t* pop = (ushort_t*)(ws + PO_OFF);

    hipLaunchKernelGGL(prep_w_kernel, dim3(192), dim3(256), 0, stream, Wq, Wk, Wv, wbt);
    hipLaunchKernelGGL(qkv_mfma_kernel, dim3(512), dim3(512), 0, stream,
                       x, wbt, bq, bk, bv, qbp, kbp, vtp);
    hipLaunchKernelGGL(attn_mfma_kernel, dim3(512, SPLIT), dim3(128), 0, stream,
                       qbp, kbp, vtp, pop, mlp);
    hipLaunchKernelGGL(merge_kernel, dim3(512), dim3(256), 0, stream, pop, mlp, out);
}

// Round 6
// 104.961 us; speedup vs baseline: 1.3317x; 1.3317x over previous
//
#include <hip/hip_runtime.h>

typedef __attribute__((ext_vector_type(4))) float f32x4;
typedef __attribute__((ext_vector_type(8))) short short8;
typedef unsigned short ushort_t;

constexpr int DM = 1024, DH = 64, S = 4096, B = 4;
// fold softmax scale 1/sqrt(64) AND log2(e) into Q so scores are in exp2 units
constexpr float QSCALE = 0.125f * 1.44269504088896340736f;

// ws layout (bytes)
constexpr size_t WBT_OFF = 0;                    // Wbt: [192][1024] bf16 (W transposed)
constexpr size_t QB_OFF  = 393216;               // Qb:  [B*S][64] bf16, pre-scaled
constexpr size_t KB_OFF  = QB_OFF + 2097152;     // Kb:  [B*S][64] bf16, LINEAR
constexpr size_t VT_OFF  = KB_OFF + 2097152;     // Vtb: [B][64][S] bf16, LINEAR

__device__ __forceinline__ ushort_t f2bf(float f) {  // RNE f32->bf16
    unsigned u = __float_as_uint(f);
    u += 0x7FFFu + ((u >> 16) & 1u);
    return (ushort_t)(u >> 16);
}

__device__ __forceinline__ void gl_lds16(const void* g, void* l) {
    __builtin_amdgcn_global_load_lds(
        (const __attribute__((address_space(1))) unsigned int*)g,
        (__attribute__((address_space(3))) unsigned int*)l, 16, 0, 0);
}

// ---------------- prep: W fp32 [1024][64] -> Wbt bf16 [192][1024] (transposed) ----
__global__ __launch_bounds__(256) void prep_w_kernel(
    const float* __restrict__ Wq, const float* __restrict__ Wk,
    const float* __restrict__ Wv, ushort_t* __restrict__ wbt)
{
    const int n = blockIdx.x;            // 0..191 : [Q(0-63)|K(64-127)|V(128-191)]
    const int p = n >> 6, d = n & 63;
    const float* W = (p == 0) ? Wq : (p == 1) ? Wk : Wv;
    const int k0 = threadIdx.x * 4;
    ushort4 pack;
    pack.x = f2bf(W[(k0 + 0) * DH + d]);
    pack.y = f2bf(W[(k0 + 1) * DH + d]);
    pack.z = f2bf(W[(k0 + 2) * DH + d]);
    pack.w = f2bf(W[(k0 + 3) * DH + d]);
    *reinterpret_cast<ushort4*>(wbt + (size_t)n * DM + k0) = pack;
}

// ---------------- QKV projection: cooperative staged GEMM (R5, kept) ----------------
__global__ __launch_bounds__(512, 4) void qkv_mfma_kernel(
    const float* __restrict__ x, const ushort_t* __restrict__ wbt,
    const float* __restrict__ bq, const float* __restrict__ bk,
    const float* __restrict__ bv,
    ushort_t* __restrict__ qb, ushort_t* __restrict__ kb, ushort_t* __restrict__ vt)
{
    __shared__ uint4 AsU[2][256];   // 2 x 4KB : [32 r][128B], 16B-chunk swz ch^(row&7)
    __shared__ uint4 BsU[2][768];   // 2 x 12KB: [192 n][64B], 16B-chunk swz ch^(row&3)

    const int tid = threadIdx.x;
    const int wid = tid >> 6, lane = tid & 63;
    const int q16 = lane & 15, lg = lane >> 4;
    const int sub = wid & 1, np = wid >> 1;
    const int r0 = blockIdx.x * 32;
    const char* xB = (const char*)x;
    const char* wB = (const char*)wbt;

    auto task = [&](int tk, int buf, int kk) {
        if (tk < 4) {
            gl_lds16(xB + (size_t)(r0 + tk * 8 + (lane >> 3)) * 4096 + kk * 4
                        + (((lane & 7) ^ (lane >> 3)) << 4),
                     (char*)&AsU[buf][0] + tk * 1024 + lane * 16);
        } else {
            const int sg = tk - 4;   // B seg 0..11 (1KB = 16 n-rows x 64B)
            gl_lds16(wB + (size_t)(sg * 16 + (lane >> 2)) * 2048 + kk * 2
                        + ((((lane & 3) ^ ((lane >> 2) & 3))) << 4),
                     (char*)&BsU[buf][0] + sg * 1024 + lane * 16);
        }
    };

    f32x4 acc[3];
#pragma unroll
    for (int j = 0; j < 3; ++j) acc[j] = {0.f, 0.f, 0.f, 0.f};

    task(2 * wid, 0, 0);
    task(2 * wid + 1, 0, 0);
    __syncthreads();

    const int row = sub * 16 + q16;
    for (int s = 0; s < 32; ++s) {
        const int buf = s & 1;
        if (s + 1 < 32) {
            task(2 * wid, buf ^ 1, (s + 1) * 32);
            task(2 * wid + 1, buf ^ 1, (s + 1) * 32);
        }
        const char* AsC = (const char*)&AsU[buf][0];
        const char* BsC = (const char*)&BsU[buf][0];
        const f32x4 a0 = *(const f32x4*)(AsC + row * 128 + (((2 * lg) ^ (row & 7)) << 4));
        const f32x4 a1 = *(const f32x4*)(AsC + row * 128 + (((2 * lg + 1) ^ (row & 7)) << 4));
        short8 Af;
        Af[0] = (short)f2bf(a0[0]); Af[1] = (short)f2bf(a0[1]);
        Af[2] = (short)f2bf(a0[2]); Af[3] = (short)f2bf(a0[3]);
        Af[4] = (short)f2bf(a1[0]); Af[5] = (short)f2bf(a1[1]);
        Af[6] = (short)f2bf(a1[2]); Af[7] = (short)f2bf(a1[3]);
        __builtin_amdgcn_s_setprio(1);
#pragma unroll
        for (int j = 0; j < 3; ++j) {
            const int nt = np * 3 + j;
            const short8 Bf = *(const short8*)(
                BsC + (nt * 16 + q16) * 64 + ((lg ^ (q16 & 3)) << 4));
            acc[j] = __builtin_amdgcn_mfma_f32_16x16x32_bf16(Af, Bf, acc[j], 0, 0, 0);
        }
        __builtin_amdgcn_s_setprio(0);
        __syncthreads();
    }

    // Epilogue: C/D layout row=(lane>>4)*4+reg, col=lane&15. Kb/Vt now LINEAR.
#pragma unroll
    for (int j = 0; j < 3; ++j) {
        const int nt = np * 3 + j;
        const int p = nt >> 2, d = ((nt & 3) << 4) + q16;
        const float* bp = (p == 0) ? bq : (p == 1) ? bk : bv;
        const float bb = bp[d];
#pragma unroll
        for (int r = 0; r < 4; ++r) {
            const int m = r0 + sub * 16 + (lg << 2) + r;
            const float v = acc[j][r] + bb;
            if (p == 0) {
                qb[(size_t)m * 64 + d] = f2bf(v * QSCALE);
            } else if (p == 1) {
                kb[(size_t)m * 64 + d] = f2bf(v);
            } else {
                const int bb_ = m >> 12, sx = m & 4095;
                vt[(size_t)bb_ * 262144 + (size_t)d * 4096 + sx] = f2bf(v);
            }
        }
    }
}

// ---------------- causal flash attention: LDS-free K/V, barrier-free tile loop ----
// Block = 256 thr (4 waves), ONE 16-row q-tile; wave w handles KV tiles t≡w (mod 4).
// K/V fragments load straight from L2-resident Kb/Vt (16B/lane, full-line use).
// Only P does a per-wave 2KB LDS roundtrip (no __syncthreads in the loop).
// End: 4-way (m,l,o) merge through 24KB LDS, all 256 threads participate.
__global__ __launch_bounds__(256, 4) void attn_mfma_kernel(
    const ushort_t* __restrict__ qb, const ushort_t* __restrict__ kb,
    const ushort_t* __restrict__ vt, float* __restrict__ out)
{
    __shared__ float Os[4][16][64];    // 16KB merge space
    __shared__ float Ml[4][2][16];     // per-wave (m,l) per q-row
    __shared__ uint2 PsU[4][256];      // 8KB: per-wave P [16 q][64 kv] bf16

    const int tid = threadIdx.x;
    const int wid = tid >> 6, lane = tid & 63;
    const int q16 = lane & 15, lg = lane >> 4;

    // XCD-pinned (2 XCDs per batch), heavy q-tiles first.
    const int linear = blockIdx.x;            // 0..1023
    const int xcd = linear & 7, idx = linear >> 3;
    const int b = xcd >> 1;
    const int qt16 = 255 - (idx * 2 + (xcd & 1));

    const int qrow = qt16 * 16 + q16;
    const ushort_t* Qb = qb + (size_t)b * S * 64;
    const ushort_t* Kb = kb + (size_t)b * S * 64;
    const ushort_t* Vt = vt + (size_t)b * 64 * S;

    const short8 qf0 = *(const short8*)(Qb + (size_t)qrow * 64 + lg * 8);
    const short8 qf1 = *(const short8*)(Qb + (size_t)qrow * 64 + 32 + lg * 8);

    f32x4 o[4];
#pragma unroll
    for (int nt = 0; nt < 4; ++nt) o[nt] = {0.f, 0.f, 0.f, 0.f};
    float m = -1e30f, l = 0.f;

    char* PsC = (char*)&PsU[wid][0];
    const int ntiles = (qt16 >> 2) + 1;

    for (int t = wid; t < ntiles; t += 4) {
        const int kv0 = t * 64;

        // ---- S^T = K . Q^T : kf = A-frag direct from Kb rows (L2-hot) ----
        f32x4 st[4];
#pragma unroll
        for (int mt = 0; mt < 4; ++mt) st[mt] = {0.f, 0.f, 0.f, 0.f};
#pragma unroll
        for (int ks = 0; ks < 2; ++ks) {
            short8 kf[4];
#pragma unroll
            for (int mt = 0; mt < 4; ++mt)
                kf[mt] = *(const short8*)(
                    Kb + (size_t)(kv0 + mt * 16 + q16) * 64 + ks * 32 + lg * 8);
            __builtin_amdgcn_s_setprio(1);
#pragma unroll
            for (int mt = 0; mt < 4; ++mt)
                st[mt] = __builtin_amdgcn_mfma_f32_16x16x32_bf16(
                    kf[mt], (ks ? qf1 : qf0), st[mt], 0, 0, 0);
            __builtin_amdgcn_s_setprio(0);
        }

        // ---- preload V frags now; L2 latency hides under softmax VALU ----
        short8 vf[8];
#pragma unroll
        for (int i = 0; i < 8; ++i) {
            const int nt = i & 3, ks = i >> 2;
            vf[i] = *(const short8*)(
                Vt + (size_t)(nt * 16 + q16) * S + kv0 + ks * 32 + lg * 8);
        }

        // ---- causal mask: only the final tile of this q-tile is boundary ----
        if (t == ntiles - 1) {
#pragma unroll
            for (int mt = 0; mt < 4; ++mt)
#pragma unroll
                for (int r = 0; r < 4; ++r)
                    if (kv0 + mt * 16 + (lg << 2) + r > qrow) st[mt][r] = -1e30f;
        }

        // ---- online softmax (log2 units), per q-column q16 ----
        float tm = -1e30f;
#pragma unroll
        for (int mt = 0; mt < 4; ++mt)
#pragma unroll
            for (int r = 0; r < 4; ++r) tm = fmaxf(tm, st[mt][r]);
        tm = fmaxf(tm, __shfl_xor(tm, 16));
        tm = fmaxf(tm, __shfl_xor(tm, 32));
        const float mn = fmaxf(m, tm);
        const float corr = exp2f(m - mn);
        float ps = 0.f;
#pragma unroll
        for (int mt = 0; mt < 4; ++mt)
#pragma unroll
            for (int r = 0; r < 4; ++r) {
                const float pv = exp2f(st[mt][r] - mn);
                st[mt][r] = pv;
                ps += pv;
            }
        ps += __shfl_xor(ps, 16);
        ps += __shfl_xor(ps, 32);
        l = l * corr + ps;
        m = mn;

        // o rows are q = 4lg+r but corr is per q-col q16 -> redistribute.
        float corr_row[4];
#pragma unroll
        for (int r = 0; r < 4; ++r) corr_row[r] = __shfl(corr, (lg << 2) | r);
#pragma unroll
        for (int nt = 0; nt < 4; ++nt)
#pragma unroll
            for (int r = 0; r < 4; ++r) o[nt][r] *= corr_row[r];

        // ---- P (bf16) -> per-wave LDS, swizzled; readback as PV A-frags ----
        // (wave-private buffer: lgkmcnt ordering only, no barrier needed)
#pragma unroll
        for (int mt = 0; mt < 4; ++mt) {
            uint2 w;
            w.x = (unsigned)f2bf(st[mt][0]) | ((unsigned)f2bf(st[mt][1]) << 16);
            w.y = (unsigned)f2bf(st[mt][2]) | ((unsigned)f2bf(st[mt][3]) << 16);
            const int ch = (2 * mt + (lg >> 1)) ^ (q16 & 7);
            *reinterpret_cast<uint2*>(PsC + q16 * 128 + ch * 16 + (lg & 1) * 8) = w;
        }
        const short8 pa0 = *reinterpret_cast<const short8*>(
            PsC + q16 * 128 + ((lg ^ (q16 & 7)) << 4));
        const short8 pa1 = *reinterpret_cast<const short8*>(
            PsC + q16 * 128 + (((lg + 4) ^ (q16 & 7)) << 4));

        // ---- O += P . V : D[q][d], row=4lg+r, col=16nt+q16 ----
        __builtin_amdgcn_s_setprio(1);
#pragma unroll
        for (int ks = 0; ks < 2; ++ks)
#pragma unroll
            for (int nt = 0; nt < 4; ++nt)
                o[nt] = __builtin_amdgcn_mfma_f32_16x16x32_bf16(
                    (ks ? pa1 : pa0), vf[ks * 4 + nt], o[nt], 0, 0, 0);
        __builtin_amdgcn_s_setprio(0);
    }

    // ---- 4-way merge via LDS: out = sum_w c_w o_w / sum_w c_w l_w ----
#pragma unroll
    for (int nt = 0; nt < 4; ++nt)
#pragma unroll
        for (int r = 0; r < 4; ++r)
            Os[wid][(lg << 2) + r][nt * 16 + q16] = o[nt][r];
    if (lg == 0) { Ml[wid][0][q16] = m; Ml[wid][1][q16] = l; }
    __syncthreads();

    const int e0 = tid << 2;            // 4 contiguous elems of the 16x64 tile
    const int row = e0 >> 6, col = e0 & 63;
    const float m0 = Ml[0][0][row], m1 = Ml[1][0][row];
    const float m2 = Ml[2][0][row], m3 = Ml[3][0][row];
    const float mm = fmaxf(fmaxf(m0, m1), fmaxf(m2, m3));
    float cz[4];
    cz[0] = exp2f(m0 - mm); cz[1] = exp2f(m1 - mm);
    cz[2] = exp2f(m2 - mm); cz[3] = exp2f(m3 - mm);
    const float L = Ml[0][1][row] * cz[0] + Ml[1][1][row] * cz[1]
                  + Ml[2][1][row] * cz[2] + Ml[3][1][row] * cz[3];
    const float inv = 1.0f / L;
    float ax = 0.f, ay = 0.f, az = 0.f, aw = 0.f;
#pragma unroll
    for (int w = 0; w < 4; ++w) {
        const float4 ov = *(const float4*)&Os[w][row][col];
        ax += cz[w] * ov.x; ay += cz[w] * ov.y;
        az += cz[w] * ov.z; aw += cz[w] * ov.w;
    }
    float* op = out + (size_t)b * S * DH + (size_t)(qt16 * 16 + row) * 64 + col;
    *(float4*)op = make_float4(ax * inv, ay * inv, az * inv, aw * inv);
}

extern "C" void kernel_launch(void* const* d_in, const int* in_sizes, int n_in,
                              void* d_out, int out_size, void* d_ws, size_t ws_size,
                              hipStream_t stream) {
    const float* x  = (const float*)d_in[0];
    const float* Wq = (const float*)d_in[1];
    const float* bq = (const float*)d_in[2];
    const float* Wk = (const float*)d_in[3];
    const float* bk = (const float*)d_in[4];
    const float* Wv = (const float*)d_in[5];
    const float* bv = (const float*)d_in[6];
    float* out = (float*)d_out;

    char* ws = (char*)d_ws;
    ushort_t* wbt = (ushort_t*)(ws + WBT_OFF);
    ushort_t* qbp = (ushort_t*)(ws + QB_OFF);
    ushort_t* kbp = (ushort_t*)(ws + KB_OFF);
    ushort_t* vtp = (ushort_t*)(ws + VT_OFF);

    hipLaunchKernelGGL(prep_w_kernel, dim3(192), dim3(256), 0, stream, Wq, Wk, Wv, wbt);
    hipLaunchKernelGGL(qkv_mfma_kernel, dim3(512), dim3(512), 0, stream,
                       x, wbt, bq, bk, bv, qbp, kbp, vtp);
    hipLaunchKernelGGL(attn_mfma_kernel, dim3(1024), dim3(256), 0, stream,
                       qbp, kbp, vtp, out);
}